// Round 1
// baseline (13564.795 us; speedup 1.0000x reference)
//
#include <hip/hip_runtime.h>
#include <hip/hip_bf16.h>

#define NN 5000
#define TT 10
#define FOUT 8
#define HH 64
#define EE 80000
#define LL 4

__device__ __forceinline__ float silu_f(float x) {
    return x / (1.0f + __expf(-x));
}

// hbuf[n][t][j] = h_in[n]*emb_w[j] + emb_b[j] + time_emb[t][j]
__global__ __launch_bounds__(256) void k_init_h(
    const float* __restrict__ h_in, const float* __restrict__ emb_w,
    const float* __restrict__ emb_b, const float* __restrict__ time_emb,
    float* __restrict__ hbuf)
{
    int idx = blockIdx.x * 256 + threadIdx.x;   // over N*T*HH
    if (idx >= NN * TT * HH) return;
    int j  = idx & (HH - 1);
    int nt = idx / HH;
    int t  = nt % TT;
    int n  = nt / TT;
    hbuf[idx] = h_in[n] * emb_w[j] + emb_b[j] + time_emb[t * HH + j];
}

// coord[n][t][0..3] = x[t][n][0..2], pad 0
__global__ __launch_bounds__(256) void k_init_coord(
    const float* __restrict__ x, float* __restrict__ coord)
{
    int i = blockIdx.x * 256 + threadIdx.x;  // over N*T
    if (i >= NN * TT) return;
    int t = i % TT, n = i / TT;
    const float* src = x + (size_t)(t * NN + n) * 3;
    float4 v;
    v.x = src[0]; v.y = src[1]; v.z = src[2]; v.w = 0.0f;
    *(float4*)(coord + (size_t)i * 4) = v;
}

// One thread per (e,t): full edge MLP chain + atomic aggregation.
__global__ __launch_bounds__(256) void k_edge(
    const float* __restrict__ hbuf, const float* __restrict__ coord,
    const int* __restrict__ edges, const float* __restrict__ eattr,
    const float* __restrict__ w1, const float* __restrict__ b1,
    const float* __restrict__ w2, const float* __restrict__ b2,
    const float* __restrict__ cw1, const float* __restrict__ cb1,
    const float* __restrict__ cw2,
    float* __restrict__ magg, float* __restrict__ agg4, float* __restrict__ cnt)
{
    int idx = blockIdx.x * 256 + threadIdx.x;
    if (idx >= EE * TT) return;
    int e = idx % EE;          // consecutive lanes -> consecutive edges
    int t = idx / EE;
    int r = edges[e];          // row (target of aggregation)
    int c = edges[EE + e];     // col
    int rt = r * TT + t, ct = c * TT + t;

    float4 cr = *(const float4*)(coord + (size_t)rt * 4);
    float4 cc = *(const float4*)(coord + (size_t)ct * 4);
    float d0 = cr.x - cc.x, d1 = cr.y - cc.y, d2 = cr.z - cc.z;
    float radial = d0 * d0 + d1 * d1 + d2 * d2;
    float ea0 = eattr[e * 2], ea1 = eattr[e * 2 + 1];

    // ---- layer 1: eh(131) @ w1(131x64) + b1, silu ----
    float a[HH];
    #pragma unroll
    for (int j = 0; j < HH; j++) a[j] = b1[j];

    const float* hr = hbuf + (size_t)rt * HH;
    const float* hc = hbuf + (size_t)ct * HH;

    for (int k0 = 0; k0 < HH; k0 += 4) {
        float4 hv = *(const float4*)(hr + k0);
        float eh[4] = {hv.x, hv.y, hv.z, hv.w};
        #pragma unroll
        for (int kk = 0; kk < 4; kk++) {
            const float* w = w1 + (size_t)(k0 + kk) * HH;
            #pragma unroll
            for (int j = 0; j < HH; j++) a[j] += eh[kk] * w[j];
        }
    }
    for (int k0 = 0; k0 < HH; k0 += 4) {
        float4 hv = *(const float4*)(hc + k0);
        float eh[4] = {hv.x, hv.y, hv.z, hv.w};
        #pragma unroll
        for (int kk = 0; kk < 4; kk++) {
            const float* w = w1 + (size_t)(HH + k0 + kk) * HH;
            #pragma unroll
            for (int j = 0; j < HH; j++) a[j] += eh[kk] * w[j];
        }
    }
    {
        const float* w = w1 + (size_t)(2 * HH) * HH;
        #pragma unroll
        for (int j = 0; j < HH; j++) a[j] += radial * w[j];
        w += HH;
        #pragma unroll
        for (int j = 0; j < HH; j++) a[j] += ea0 * w[j];
        w += HH;
        #pragma unroll
        for (int j = 0; j < HH; j++) a[j] += ea1 * w[j];
    }
    #pragma unroll
    for (int j = 0; j < HH; j++) a[j] = silu_f(a[j]);

    // ---- layer 2: m = silu(a @ w2 + b2) ----
    float m[HH];
    #pragma unroll
    for (int j = 0; j < HH; j++) m[j] = b2[j];
    #pragma unroll
    for (int k = 0; k < HH; k++) {          // fully unrolled: a[k] static
        const float* w = w2 + (size_t)k * HH;
        float s = a[k];
        #pragma unroll
        for (int j = 0; j < HH; j++) m[j] += s * w[j];
    }
    #pragma unroll
    for (int j = 0; j < HH; j++) m[j] = silu_f(m[j]);

    // ---- coord MLP: cm = silu(m @ cw1 + cb1) @ cw2 ----
    #pragma unroll
    for (int j = 0; j < HH; j++) a[j] = cb1[j];   // reuse a[]
    #pragma unroll
    for (int k = 0; k < HH; k++) {
        const float* w = cw1 + (size_t)k * HH;
        float s = m[k];
        #pragma unroll
        for (int j = 0; j < HH; j++) a[j] += s * w[j];
    }
    float cm = 0.0f;
    #pragma unroll
    for (int j = 0; j < HH; j++) cm += silu_f(a[j]) * cw2[j];

    // ---- aggregate: trans into agg4[rt], count, m into magg[rt] ----
    float* ag = agg4 + (size_t)rt * 4;
    atomicAdd(ag + 0, d0 * cm);
    atomicAdd(ag + 1, d1 * cm);
    atomicAdd(ag + 2, d2 * cm);
    atomicAdd(cnt + rt, 1.0f);

    float* mg = magg + (size_t)rt * HH;
    #pragma unroll
    for (int j = 0; j < HH; j++) atomicAdd(mg + j, m[j]);
}

// coord += agg / max(cnt,1)
__global__ __launch_bounds__(256) void k_coord_upd(
    float* __restrict__ coord, const float* __restrict__ agg4,
    const float* __restrict__ cnt)
{
    int i = blockIdx.x * 256 + threadIdx.x;
    if (i >= NN * TT) return;
    float inv = 1.0f / fmaxf(cnt[i], 1.0f);
    float4 cv = *(float4*)(coord + (size_t)i * 4);
    float4 av = *(const float4*)(agg4 + (size_t)i * 4);
    cv.x += av.x * inv; cv.y += av.y * inv; cv.z += av.z * inv;
    *(float4*)(coord + (size_t)i * 4) = cv;
}

// node MLP with residual, in place: h += silu([h,magg]@w1+b1)@w2 + b2
__global__ __launch_bounds__(256) void k_node(
    float* __restrict__ hbuf, const float* __restrict__ magg,
    const float* __restrict__ w1, const float* __restrict__ b1,
    const float* __restrict__ w2, const float* __restrict__ b2)
{
    int i = blockIdx.x * 256 + threadIdx.x;  // n*T+t
    if (i >= NN * TT) return;
    float* hp = hbuf + (size_t)i * HH;
    const float* mp = magg + (size_t)i * HH;

    float a[HH];
    #pragma unroll
    for (int j = 0; j < HH; j++) a[j] = b1[j];

    for (int k0 = 0; k0 < HH; k0 += 4) {
        float4 v = *(const float4*)(hp + k0);
        float s[4] = {v.x, v.y, v.z, v.w};
        #pragma unroll
        for (int kk = 0; kk < 4; kk++) {
            const float* w = w1 + (size_t)(k0 + kk) * HH;
            #pragma unroll
            for (int j = 0; j < HH; j++) a[j] += s[kk] * w[j];
        }
    }
    for (int k0 = 0; k0 < HH; k0 += 4) {
        float4 v = *(const float4*)(mp + k0);
        float s[4] = {v.x, v.y, v.z, v.w};
        #pragma unroll
        for (int kk = 0; kk < 4; kk++) {
            const float* w = w1 + (size_t)(HH + k0 + kk) * HH;
            #pragma unroll
            for (int j = 0; j < HH; j++) a[j] += s[kk] * w[j];
        }
    }
    #pragma unroll
    for (int j = 0; j < HH; j++) a[j] = silu_f(a[j]);

    float o[HH];
    #pragma unroll
    for (int j = 0; j < HH; j++) o[j] = b2[j];
    #pragma unroll
    for (int k = 0; k < HH; k++) {
        const float* w = w2 + (size_t)k * HH;
        float s = a[k];
        #pragma unroll
        for (int j = 0; j < HH; j++) o[j] += s * w[j];
    }
    #pragma unroll
    for (int j = 0; j < HH; j++) hp[j] = hp[j] + o[j];
}

// out[f][n][c] = sum_t softmax(theta[f])[t] * coord[n][t][c]
__global__ __launch_bounds__(256) void k_final(
    const float* __restrict__ coord, const float* __restrict__ theta,
    float* __restrict__ out)
{
    int i = blockIdx.x * 256 + threadIdx.x;  // f*N + n
    if (i >= FOUT * NN) return;
    int f = i / NN, n = i % NN;

    float w[TT];
    float mx = -1e30f;
    #pragma unroll
    for (int t = 0; t < TT; t++) { w[t] = theta[f * TT + t]; mx = fmaxf(mx, w[t]); }
    float s = 0.0f;
    #pragma unroll
    for (int t = 0; t < TT; t++) { w[t] = __expf(w[t] - mx); s += w[t]; }
    float inv = 1.0f / s;
    float o0 = 0.f, o1 = 0.f, o2 = 0.f;
    #pragma unroll
    for (int t = 0; t < TT; t++) {
        float4 cv = *(const float4*)(coord + (size_t)(n * TT + t) * 4);
        float ww = w[t] * inv;
        o0 += ww * cv.x; o1 += ww * cv.y; o2 += ww * cv.z;
    }
    float* op = out + (size_t)(f * NN + n) * 3;
    op[0] = o0; op[1] = o1; op[2] = o2;
}

extern "C" void kernel_launch(void* const* d_in, const int* in_sizes, int n_in,
                              void* d_out, int out_size, void* d_ws, size_t ws_size,
                              hipStream_t stream)
{
    const float* h_in     = (const float*)d_in[0];
    const float* x        = (const float*)d_in[1];
    const int*   edges    = (const int*)d_in[2];
    const float* eattr    = (const float*)d_in[3];
    const float* emb_w    = (const float*)d_in[4];
    const float* emb_b    = (const float*)d_in[5];
    const float* time_emb = (const float*)d_in[6];
    const float* theta    = (const float*)d_in[7];
    const float* ew1 = (const float*)d_in[8];
    const float* eb1 = (const float*)d_in[9];
    const float* ew2 = (const float*)d_in[10];
    const float* eb2 = (const float*)d_in[11];
    const float* nw1 = (const float*)d_in[12];
    const float* nb1 = (const float*)d_in[13];
    const float* nw2 = (const float*)d_in[14];
    const float* nb2 = (const float*)d_in[15];
    const float* cw1 = (const float*)d_in[16];
    const float* cb1 = (const float*)d_in[17];
    const float* cw2 = (const float*)d_in[18];
    float* out = (float*)d_out;

    float* ws    = (float*)d_ws;
    float* hbuf  = ws;                        // N*T*64
    float* coord = hbuf + (size_t)NN * TT * HH;   // N*T*4
    float* magg  = coord + (size_t)NN * TT * 4;   // N*T*64
    float* agg4  = magg + (size_t)NN * TT * HH;   // N*T*4
    float* cnt   = agg4 + (size_t)NN * TT * 4;    // N*T

    hipLaunchKernelGGL(k_init_h, dim3((NN * TT * HH + 255) / 256), dim3(256), 0, stream,
                       h_in, emb_w, emb_b, time_emb, hbuf);
    hipLaunchKernelGGL(k_init_coord, dim3((NN * TT + 255) / 256), dim3(256), 0, stream,
                       x, coord);

    const int K1 = 2 * HH + 3;  // 131
    for (int l = 0; l < LL; l++) {
        // zero magg + agg4 + cnt (contiguous in ws)
        hipMemsetAsync(magg, 0,
                       (size_t)(NN * TT * HH + NN * TT * 4 + NN * TT) * sizeof(float),
                       stream);
        hipLaunchKernelGGL(k_edge, dim3((EE * TT + 255) / 256), dim3(256), 0, stream,
            hbuf, coord, edges, eattr,
            ew1 + (size_t)l * K1 * HH, eb1 + (size_t)l * HH,
            ew2 + (size_t)l * HH * HH, eb2 + (size_t)l * HH,
            cw1 + (size_t)l * HH * HH, cb1 + (size_t)l * HH,
            cw2 + (size_t)l * HH,
            magg, agg4, cnt);
        hipLaunchKernelGGL(k_coord_upd, dim3((NN * TT + 255) / 256), dim3(256), 0, stream,
            coord, agg4, cnt);
        hipLaunchKernelGGL(k_node, dim3((NN * TT + 255) / 256), dim3(256), 0, stream,
            hbuf, magg,
            nw1 + (size_t)l * 2 * HH * HH, nb1 + (size_t)l * HH,
            nw2 + (size_t)l * HH * HH, nb2 + (size_t)l * HH);
    }
    hipLaunchKernelGGL(k_final, dim3((FOUT * NN + 255) / 256), dim3(256), 0, stream,
        coord, theta, out);
}

// Round 2
// 10334.720 us; speedup vs baseline: 1.3125x; 1.3125x over previous
//
#include <hip/hip_runtime.h>
#include <hip/hip_bf16.h>

#define NN 5000
#define TT 10
#define FOUT 8
#define HH 64
#define EE 80000
#define LL 4

__device__ __forceinline__ float silu_f(float x) {
    return x / (1.0f + __expf(-x));
}

// ---------------------------------------------------------------- init
__global__ __launch_bounds__(256) void k_init_h(
    const float* __restrict__ h_in, const float* __restrict__ emb_w,
    const float* __restrict__ emb_b, const float* __restrict__ time_emb,
    float* __restrict__ hbuf)
{
    int idx = blockIdx.x * 256 + threadIdx.x;   // over N*T*HH
    if (idx >= NN * TT * HH) return;
    int j  = idx & (HH - 1);
    int nt = idx / HH;
    int t  = nt % TT;
    int n  = nt / TT;
    hbuf[idx] = h_in[n] * emb_w[j] + emb_b[j] + time_emb[t * HH + j];
}

__global__ __launch_bounds__(256) void k_init_coord(
    const float* __restrict__ x, float* __restrict__ coord)
{
    int i = blockIdx.x * 256 + threadIdx.x;  // over N*T
    if (i >= NN * TT) return;
    int t = i % TT, n = i / TT;
    const float* src = x + (size_t)(t * NN + n) * 3;
    float4 v;
    v.x = src[0]; v.y = src[1]; v.z = src[2]; v.w = 0.0f;
    *(float4*)(coord + (size_t)i * 4) = v;
}

// ---------------------------------------------------------------- CSR build
__global__ __launch_bounds__(256) void k_deg(
    const int* __restrict__ edges, int* __restrict__ deg)
{
    int e = blockIdx.x * 256 + threadIdx.x;
    if (e >= EE) return;
    atomicAdd(deg + edges[e], 1);
}

// single block of 256: exclusive scan of deg[0..NN) -> rowptr, woff
__global__ __launch_bounds__(256) void k_scan(
    const int* __restrict__ deg, int* __restrict__ rowptr, int* __restrict__ woff)
{
    __shared__ int sums[256];
    int tid = threadIdx.x;
    const int CH = (NN + 255) / 256;  // 20
    int base = tid * CH;
    int s = 0;
    for (int i = 0; i < CH; i++) {
        int idx = base + i;
        if (idx < NN) s += deg[idx];
    }
    sums[tid] = s;
    __syncthreads();
    for (int off = 1; off < 256; off <<= 1) {
        int other = (tid >= off) ? sums[tid - off] : 0;
        __syncthreads();
        sums[tid] += other;
        __syncthreads();
    }
    int run = sums[tid] - s;  // exclusive offset of this chunk
    for (int i = 0; i < CH; i++) {
        int idx = base + i;
        if (idx < NN) {
            rowptr[idx] = run;
            woff[idx] = run;
            run += deg[idx];
        }
    }
    if (tid == 255) rowptr[NN] = run;
}

__global__ __launch_bounds__(256) void k_scatter(
    const int* __restrict__ edges, int* __restrict__ woff, int* __restrict__ eidx)
{
    int e = blockIdx.x * 256 + threadIdx.x;
    if (e >= EE) return;
    int pos = atomicAdd(woff + edges[e], 1);
    eidx[pos] = e;
}

// ---------------------------------------------------------------- edge MLP (no atomics)
__global__ __launch_bounds__(256) void k_edge2(
    const float* __restrict__ hbuf, const float* __restrict__ coord,
    const int* __restrict__ edges, const float* __restrict__ eattr,
    const float* __restrict__ w1, const float* __restrict__ b1,
    const float* __restrict__ w2, const float* __restrict__ b2,
    const float* __restrict__ cw1, const float* __restrict__ cb1,
    const float* __restrict__ cw2,
    float* __restrict__ mbuf, float* __restrict__ trans4)
{
    int idx = blockIdx.x * 256 + threadIdx.x;
    if (idx >= EE * TT) return;
    int e = idx % EE;          // consecutive lanes -> consecutive edges
    int t = idx / EE;
    int r = edges[e];
    int c = edges[EE + e];
    int rt = r * TT + t, ct = c * TT + t;

    float4 cr = *(const float4*)(coord + (size_t)rt * 4);
    float4 cc = *(const float4*)(coord + (size_t)ct * 4);
    float d0 = cr.x - cc.x, d1 = cr.y - cc.y, d2 = cr.z - cc.z;
    float radial = d0 * d0 + d1 * d1 + d2 * d2;
    float ea0 = eattr[e * 2], ea1 = eattr[e * 2 + 1];

    // ---- layer 1: eh(131) @ w1(131x64) + b1, silu ----
    float a[HH];
    #pragma unroll
    for (int j = 0; j < HH; j++) a[j] = b1[j];

    const float* hr = hbuf + (size_t)rt * HH;
    const float* hc = hbuf + (size_t)ct * HH;

    for (int k0 = 0; k0 < HH; k0 += 4) {
        float4 hv = *(const float4*)(hr + k0);
        float eh[4] = {hv.x, hv.y, hv.z, hv.w};
        #pragma unroll
        for (int kk = 0; kk < 4; kk++) {
            const float* w = w1 + (size_t)(k0 + kk) * HH;
            #pragma unroll
            for (int j = 0; j < HH; j++) a[j] += eh[kk] * w[j];
        }
    }
    for (int k0 = 0; k0 < HH; k0 += 4) {
        float4 hv = *(const float4*)(hc + k0);
        float eh[4] = {hv.x, hv.y, hv.z, hv.w};
        #pragma unroll
        for (int kk = 0; kk < 4; kk++) {
            const float* w = w1 + (size_t)(HH + k0 + kk) * HH;
            #pragma unroll
            for (int j = 0; j < HH; j++) a[j] += eh[kk] * w[j];
        }
    }
    {
        const float* w = w1 + (size_t)(2 * HH) * HH;
        #pragma unroll
        for (int j = 0; j < HH; j++) a[j] += radial * w[j];
        w += HH;
        #pragma unroll
        for (int j = 0; j < HH; j++) a[j] += ea0 * w[j];
        w += HH;
        #pragma unroll
        for (int j = 0; j < HH; j++) a[j] += ea1 * w[j];
    }
    #pragma unroll
    for (int j = 0; j < HH; j++) a[j] = silu_f(a[j]);

    // ---- layer 2: m = silu(a @ w2 + b2) ----
    float mr[HH];
    #pragma unroll
    for (int j = 0; j < HH; j++) mr[j] = b2[j];
    #pragma unroll
    for (int k = 0; k < HH; k++) {
        const float* w = w2 + (size_t)k * HH;
        float s = a[k];
        #pragma unroll
        for (int j = 0; j < HH; j++) mr[j] += s * w[j];
    }
    #pragma unroll
    for (int j = 0; j < HH; j++) mr[j] = silu_f(mr[j]);

    // ---- coord MLP: cm = silu(m @ cw1 + cb1) @ cw2 ----
    #pragma unroll
    for (int j = 0; j < HH; j++) a[j] = cb1[j];   // reuse a[]
    #pragma unroll
    for (int k = 0; k < HH; k++) {
        const float* w = cw1 + (size_t)k * HH;
        float s = mr[k];
        #pragma unroll
        for (int j = 0; j < HH; j++) a[j] += s * w[j];
    }
    float cm = 0.0f;
    #pragma unroll
    for (int j = 0; j < HH; j++) cm += silu_f(a[j]) * cw2[j];

    // ---- stores: m[e][t][:], trans4[e][t][:] ----
    float* mp = mbuf + ((size_t)e * TT + t) * HH;
    #pragma unroll
    for (int j = 0; j < HH; j += 4) {
        float4 v; v.x = mr[j]; v.y = mr[j+1]; v.z = mr[j+2]; v.w = mr[j+3];
        *(float4*)(mp + j) = v;
    }
    float4 tv; tv.x = d0 * cm; tv.y = d1 * cm; tv.z = d2 * cm; tv.w = 0.0f;
    *(float4*)(trans4 + ((size_t)e * TT + t) * 4) = tv;
}

// ---------------------------------------------------------------- gather: magg + coord update
__global__ __launch_bounds__(64) void k_gather(
    const float* __restrict__ mbuf, const float* __restrict__ trans4,
    const int* __restrict__ rowptr, const int* __restrict__ eidx,
    float* __restrict__ magg, float* __restrict__ coord)
{
    int b = blockIdx.x;           // n*TT + t
    int n = b / TT, t = b % TT;
    int lane = threadIdx.x;
    int start = rowptr[n], end = rowptr[n + 1];

    float s = 0.0f;
    for (int i = start; i < end; i++) {
        int e = eidx[i];                                     // scalar, broadcast
        s += mbuf[((size_t)e * TT + t) * HH + lane];         // coalesced 256B
    }
    magg[((size_t)n * TT + t) * HH + lane] = s;

    // trans reduction: lane = (k0<<2)|c ; c = component, k0 = edge stride-16 slot
    int c = lane & 3, k0 = lane >> 2;
    float p = 0.0f;
    for (int i = start + k0; i < end; i += 16) {
        int e = eidx[i];
        p += trans4[((size_t)e * TT + t) * 4 + c];
    }
    #pragma unroll
    for (int off = 4; off < 64; off <<= 1) p += __shfl_xor(p, off);
    if (lane < 3) {
        float cntf = (float)(end - start);
        coord[(size_t)b * 4 + lane] += p / fmaxf(cntf, 1.0f);
    }
}

// ---------------------------------------------------------------- atomic fallback path
__global__ __launch_bounds__(256) void k_edge_atomic(
    const float* __restrict__ hbuf, const float* __restrict__ coord,
    const int* __restrict__ edges, const float* __restrict__ eattr,
    const float* __restrict__ w1, const float* __restrict__ b1,
    const float* __restrict__ w2, const float* __restrict__ b2,
    const float* __restrict__ cw1, const float* __restrict__ cb1,
    const float* __restrict__ cw2,
    float* __restrict__ magg, float* __restrict__ agg4, float* __restrict__ cnt)
{
    int idx = blockIdx.x * 256 + threadIdx.x;
    if (idx >= EE * TT) return;
    int e = idx % EE;
    int t = idx / EE;
    int r = edges[e];
    int c = edges[EE + e];
    int rt = r * TT + t, ct = c * TT + t;

    float4 cr = *(const float4*)(coord + (size_t)rt * 4);
    float4 cc = *(const float4*)(coord + (size_t)ct * 4);
    float d0 = cr.x - cc.x, d1 = cr.y - cc.y, d2 = cr.z - cc.z;
    float radial = d0 * d0 + d1 * d1 + d2 * d2;
    float ea0 = eattr[e * 2], ea1 = eattr[e * 2 + 1];

    float a[HH];
    #pragma unroll
    for (int j = 0; j < HH; j++) a[j] = b1[j];
    const float* hr = hbuf + (size_t)rt * HH;
    const float* hc = hbuf + (size_t)ct * HH;
    for (int k0 = 0; k0 < HH; k0 += 4) {
        float4 hv = *(const float4*)(hr + k0);
        float eh[4] = {hv.x, hv.y, hv.z, hv.w};
        #pragma unroll
        for (int kk = 0; kk < 4; kk++) {
            const float* w = w1 + (size_t)(k0 + kk) * HH;
            #pragma unroll
            for (int j = 0; j < HH; j++) a[j] += eh[kk] * w[j];
        }
    }
    for (int k0 = 0; k0 < HH; k0 += 4) {
        float4 hv = *(const float4*)(hc + k0);
        float eh[4] = {hv.x, hv.y, hv.z, hv.w};
        #pragma unroll
        for (int kk = 0; kk < 4; kk++) {
            const float* w = w1 + (size_t)(HH + k0 + kk) * HH;
            #pragma unroll
            for (int j = 0; j < HH; j++) a[j] += eh[kk] * w[j];
        }
    }
    {
        const float* w = w1 + (size_t)(2 * HH) * HH;
        #pragma unroll
        for (int j = 0; j < HH; j++) a[j] += radial * w[j];
        w += HH;
        #pragma unroll
        for (int j = 0; j < HH; j++) a[j] += ea0 * w[j];
        w += HH;
        #pragma unroll
        for (int j = 0; j < HH; j++) a[j] += ea1 * w[j];
    }
    #pragma unroll
    for (int j = 0; j < HH; j++) a[j] = silu_f(a[j]);

    float mr[HH];
    #pragma unroll
    for (int j = 0; j < HH; j++) mr[j] = b2[j];
    #pragma unroll
    for (int k = 0; k < HH; k++) {
        const float* w = w2 + (size_t)k * HH;
        float s = a[k];
        #pragma unroll
        for (int j = 0; j < HH; j++) mr[j] += s * w[j];
    }
    #pragma unroll
    for (int j = 0; j < HH; j++) mr[j] = silu_f(mr[j]);

    #pragma unroll
    for (int j = 0; j < HH; j++) a[j] = cb1[j];
    #pragma unroll
    for (int k = 0; k < HH; k++) {
        const float* w = cw1 + (size_t)k * HH;
        float s = mr[k];
        #pragma unroll
        for (int j = 0; j < HH; j++) a[j] += s * w[j];
    }
    float cm = 0.0f;
    #pragma unroll
    for (int j = 0; j < HH; j++) cm += silu_f(a[j]) * cw2[j];

    float* ag = agg4 + (size_t)rt * 4;
    atomicAdd(ag + 0, d0 * cm);
    atomicAdd(ag + 1, d1 * cm);
    atomicAdd(ag + 2, d2 * cm);
    atomicAdd(cnt + rt, 1.0f);
    float* mg = magg + (size_t)rt * HH;
    #pragma unroll
    for (int j = 0; j < HH; j++) atomicAdd(mg + j, mr[j]);
}

__global__ __launch_bounds__(256) void k_coord_upd(
    float* __restrict__ coord, const float* __restrict__ agg4,
    const float* __restrict__ cnt)
{
    int i = blockIdx.x * 256 + threadIdx.x;
    if (i >= NN * TT) return;
    float inv = 1.0f / fmaxf(cnt[i], 1.0f);
    float4 cv = *(float4*)(coord + (size_t)i * 4);
    float4 av = *(const float4*)(agg4 + (size_t)i * 4);
    cv.x += av.x * inv; cv.y += av.y * inv; cv.z += av.z * inv;
    *(float4*)(coord + (size_t)i * 4) = cv;
}

// ---------------------------------------------------------------- node MLP
__global__ __launch_bounds__(256) void k_node(
    float* __restrict__ hbuf, const float* __restrict__ magg,
    const float* __restrict__ w1, const float* __restrict__ b1,
    const float* __restrict__ w2, const float* __restrict__ b2)
{
    int i = blockIdx.x * 256 + threadIdx.x;  // n*T+t
    if (i >= NN * TT) return;
    float* hp = hbuf + (size_t)i * HH;
    const float* mp = magg + (size_t)i * HH;

    float a[HH];
    #pragma unroll
    for (int j = 0; j < HH; j++) a[j] = b1[j];

    for (int k0 = 0; k0 < HH; k0 += 4) {
        float4 v = *(const float4*)(hp + k0);
        float s[4] = {v.x, v.y, v.z, v.w};
        #pragma unroll
        for (int kk = 0; kk < 4; kk++) {
            const float* w = w1 + (size_t)(k0 + kk) * HH;
            #pragma unroll
            for (int j = 0; j < HH; j++) a[j] += s[kk] * w[j];
        }
    }
    for (int k0 = 0; k0 < HH; k0 += 4) {
        float4 v = *(const float4*)(mp + k0);
        float s[4] = {v.x, v.y, v.z, v.w};
        #pragma unroll
        for (int kk = 0; kk < 4; kk++) {
            const float* w = w1 + (size_t)(HH + k0 + kk) * HH;
            #pragma unroll
            for (int j = 0; j < HH; j++) a[j] += s[kk] * w[j];
        }
    }
    #pragma unroll
    for (int j = 0; j < HH; j++) a[j] = silu_f(a[j]);

    float o[HH];
    #pragma unroll
    for (int j = 0; j < HH; j++) o[j] = b2[j];
    #pragma unroll
    for (int k = 0; k < HH; k++) {
        const float* w = w2 + (size_t)k * HH;
        float s = a[k];
        #pragma unroll
        for (int j = 0; j < HH; j++) o[j] += s * w[j];
    }
    #pragma unroll
    for (int j = 0; j < HH; j++) hp[j] = hp[j] + o[j];
}

// ---------------------------------------------------------------- readout
__global__ __launch_bounds__(256) void k_final(
    const float* __restrict__ coord, const float* __restrict__ theta,
    float* __restrict__ out)
{
    int i = blockIdx.x * 256 + threadIdx.x;  // f*N + n
    if (i >= FOUT * NN) return;
    int f = i / NN, n = i % NN;

    float w[TT];
    float mx = -1e30f;
    #pragma unroll
    for (int t = 0; t < TT; t++) { w[t] = theta[f * TT + t]; mx = fmaxf(mx, w[t]); }
    float s = 0.0f;
    #pragma unroll
    for (int t = 0; t < TT; t++) { w[t] = __expf(w[t] - mx); s += w[t]; }
    float inv = 1.0f / s;
    float o0 = 0.f, o1 = 0.f, o2 = 0.f;
    #pragma unroll
    for (int t = 0; t < TT; t++) {
        float4 cv = *(const float4*)(coord + (size_t)(n * TT + t) * 4);
        float ww = w[t] * inv;
        o0 += ww * cv.x; o1 += ww * cv.y; o2 += ww * cv.z;
    }
    float* op = out + (size_t)(f * NN + n) * 3;
    op[0] = o0; op[1] = o1; op[2] = o2;
}

extern "C" void kernel_launch(void* const* d_in, const int* in_sizes, int n_in,
                              void* d_out, int out_size, void* d_ws, size_t ws_size,
                              hipStream_t stream)
{
    const float* h_in     = (const float*)d_in[0];
    const float* x        = (const float*)d_in[1];
    const int*   edges    = (const int*)d_in[2];
    const float* eattr    = (const float*)d_in[3];
    const float* emb_w    = (const float*)d_in[4];
    const float* emb_b    = (const float*)d_in[5];
    const float* time_emb = (const float*)d_in[6];
    const float* theta    = (const float*)d_in[7];
    const float* ew1 = (const float*)d_in[8];
    const float* eb1 = (const float*)d_in[9];
    const float* ew2 = (const float*)d_in[10];
    const float* eb2 = (const float*)d_in[11];
    const float* nw1 = (const float*)d_in[12];
    const float* nb1 = (const float*)d_in[13];
    const float* nw2 = (const float*)d_in[14];
    const float* nb2 = (const float*)d_in[15];
    const float* cw1 = (const float*)d_in[16];
    const float* cb1 = (const float*)d_in[17];
    const float* cw2 = (const float*)d_in[18];
    float* out = (float*)d_out;

    const int K1 = 2 * HH + 3;  // 131

    // ---- workspace carve (floats) ----
    float* ws    = (float*)d_ws;
    float* hbuf  = ws;                                  // N*T*64
    float* coord = hbuf + (size_t)NN * TT * HH;         // N*T*4
    float* magg  = coord + (size_t)NN * TT * 4;         // N*T*64
    float* tail  = magg + (size_t)NN * TT * HH;

    // new-path buffers
    float* mbuf   = tail;                               // E*T*64
    float* trans4 = mbuf + (size_t)EE * TT * HH;        // E*T*4
    int*   ibuf   = (int*)(trans4 + (size_t)EE * TT * 4);
    int*   deg    = ibuf;                               // N
    int*   rowptr = deg + NN;                           // N+1
    int*   woff   = rowptr + NN + 1;                    // N
    int*   eidx   = woff + NN;                          // E
    size_t need = (size_t)((char*)(eidx + EE) - (char*)d_ws);

    hipLaunchKernelGGL(k_init_h, dim3((NN * TT * HH + 255) / 256), dim3(256), 0, stream,
                       h_in, emb_w, emb_b, time_emb, hbuf);
    hipLaunchKernelGGL(k_init_coord, dim3((NN * TT + 255) / 256), dim3(256), 0, stream,
                       x, coord);

    if (ws_size >= need) {
        // ---- CSR build (once per launch) ----
        hipMemsetAsync(deg, 0, (size_t)NN * sizeof(int), stream);
        hipLaunchKernelGGL(k_deg, dim3((EE + 255) / 256), dim3(256), 0, stream, edges, deg);
        hipLaunchKernelGGL(k_scan, dim3(1), dim3(256), 0, stream, deg, rowptr, woff);
        hipLaunchKernelGGL(k_scatter, dim3((EE + 255) / 256), dim3(256), 0, stream,
                           edges, woff, eidx);

        for (int l = 0; l < LL; l++) {
            hipLaunchKernelGGL(k_edge2, dim3((EE * TT + 255) / 256), dim3(256), 0, stream,
                hbuf, coord, edges, eattr,
                ew1 + (size_t)l * K1 * HH, eb1 + (size_t)l * HH,
                ew2 + (size_t)l * HH * HH, eb2 + (size_t)l * HH,
                cw1 + (size_t)l * HH * HH, cb1 + (size_t)l * HH,
                cw2 + (size_t)l * HH,
                mbuf, trans4);
            hipLaunchKernelGGL(k_gather, dim3(NN * TT), dim3(64), 0, stream,
                mbuf, trans4, rowptr, eidx, magg, coord);
            hipLaunchKernelGGL(k_node, dim3((NN * TT + 255) / 256), dim3(256), 0, stream,
                hbuf, magg,
                nw1 + (size_t)l * 2 * HH * HH, nb1 + (size_t)l * HH,
                nw2 + (size_t)l * HH * HH, nb2 + (size_t)l * HH);
        }
    } else {
        // ---- fallback: atomic path (round-1 behavior) ----
        float* agg4 = tail;                             // N*T*4
        float* cnt  = agg4 + (size_t)NN * TT * 4;       // N*T
        for (int l = 0; l < LL; l++) {
            hipMemsetAsync(magg, 0, (size_t)NN * TT * HH * sizeof(float), stream);
            hipMemsetAsync(agg4, 0, (size_t)(NN * TT * 4 + NN * TT) * sizeof(float), stream);
            hipLaunchKernelGGL(k_edge_atomic, dim3((EE * TT + 255) / 256), dim3(256), 0, stream,
                hbuf, coord, edges, eattr,
                ew1 + (size_t)l * K1 * HH, eb1 + (size_t)l * HH,
                ew2 + (size_t)l * HH * HH, eb2 + (size_t)l * HH,
                cw1 + (size_t)l * HH * HH, cb1 + (size_t)l * HH,
                cw2 + (size_t)l * HH,
                magg, agg4, cnt);
            hipLaunchKernelGGL(k_coord_upd, dim3((NN * TT + 255) / 256), dim3(256), 0, stream,
                coord, agg4, cnt);
            hipLaunchKernelGGL(k_node, dim3((NN * TT + 255) / 256), dim3(256), 0, stream,
                hbuf, magg,
                nw1 + (size_t)l * 2 * HH * HH, nb1 + (size_t)l * HH,
                nw2 + (size_t)l * HH * HH, nb2 + (size_t)l * HH);
        }
    }

    hipLaunchKernelGGL(k_final, dim3((FOUT * NN + 255) / 256), dim3(256), 0, stream,
        coord, theta, out);
}

// Round 3
// 1213.688 us; speedup vs baseline: 11.1765x; 8.5151x over previous
//
#include <hip/hip_runtime.h>
#include <hip/hip_bf16.h>

#define NN 5000
#define TT 10
#define FOUT 8
#define HH 64
#define EE 80000
#define LL 4

#define STR1 136            // WT1 k-stride (128 used + 8 pad)
#define STR2 72             // WT2/CT1/act k-stride (64 used + 8 pad)
#define WT1_OFF 0           // ushort offsets inside one layer's wpack block
#define WT2_OFF 8704        // 64*136
#define CT1_OFF 13312       // + 64*72
#define WPACK_PER_LAYER 17920  // + 64*72

typedef __attribute__((ext_vector_type(8))) short short8;
typedef __attribute__((ext_vector_type(4))) float f32x4;

__device__ __forceinline__ float silu_f(float x) {
    return x / (1.0f + __expf(-x));
}
__device__ __forceinline__ float bf2f(unsigned short u) {
    return __uint_as_float(((unsigned int)u) << 16);
}
__device__ __forceinline__ unsigned short f2bf(float x) {   // RNE
    unsigned int u = __float_as_uint(x);
    u += 0x7fffu + ((u >> 16) & 1u);
    return (unsigned short)(u >> 16);
}

// ---------------------------------------------------------------- init
__global__ __launch_bounds__(256) void k_init_h(
    const float* __restrict__ h_in, const float* __restrict__ emb_w,
    const float* __restrict__ emb_b, const float* __restrict__ time_emb,
    unsigned short* __restrict__ hbuf)
{
    int idx = blockIdx.x * 256 + threadIdx.x;   // over N*T*HH
    if (idx >= NN * TT * HH) return;
    int j  = idx & (HH - 1);
    int nt = idx / HH;
    int t  = nt % TT;
    int n  = nt / TT;
    hbuf[idx] = f2bf(h_in[n] * emb_w[j] + emb_b[j] + time_emb[t * HH + j]);
}

__global__ __launch_bounds__(256) void k_init_coord(
    const float* __restrict__ x, float* __restrict__ coord)
{
    int i = blockIdx.x * 256 + threadIdx.x;  // over N*T
    if (i >= NN * TT) return;
    int t = i % TT, n = i / TT;
    const float* src = x + (size_t)(t * NN + n) * 3;
    float4 v;
    v.x = src[0]; v.y = src[1]; v.z = src[2]; v.w = 0.0f;
    *(float4*)(coord + (size_t)i * 4) = v;
}

// ---------------------------------------------------------------- weight prep (f32 -> bf16, transposed+padded)
__global__ __launch_bounds__(256) void k_prep(
    const float* __restrict__ ew1, const float* __restrict__ ew2,
    const float* __restrict__ cw1, unsigned short* __restrict__ wpack)
{
    int idx = blockIdx.x * 256 + threadIdx.x;
    if (idx >= LL * WPACK_PER_LAYER) return;
    int l = idx / WPACK_PER_LAYER, o = idx % WPACK_PER_LAYER;
    float v = 0.0f;
    if (o < WT2_OFF) {                       // WT1[col][k] = ew1[l][k][col], k<128
        int cc = o / STR1, k = o % STR1;
        if (k < 128) v = ew1[(size_t)l * 131 * 64 + (size_t)k * 64 + cc];
    } else if (o < CT1_OFF) {                // WT2[col][k] = ew2[l][k][col]
        int o2 = o - WT2_OFF; int cc = o2 / STR2, k = o2 % STR2;
        if (k < 64) v = ew2[(size_t)l * 4096 + (size_t)k * 64 + cc];
    } else {                                 // CT1[col][k] = cw1[l][k][col]
        int o3 = o - CT1_OFF; int cc = o3 / STR2, k = o3 % STR2;
        if (k < 64) v = cw1[(size_t)l * 4096 + (size_t)k * 64 + cc];
    }
    wpack[idx] = f2bf(v);
}

// ---------------------------------------------------------------- CSR build
__global__ __launch_bounds__(256) void k_deg(
    const int* __restrict__ edges, int* __restrict__ deg)
{
    int e = blockIdx.x * 256 + threadIdx.x;
    if (e >= EE) return;
    atomicAdd(deg + edges[e], 1);
}

__global__ __launch_bounds__(256) void k_scan(
    const int* __restrict__ deg, int* __restrict__ rowptr, int* __restrict__ woff)
{
    __shared__ int sums[256];
    int tid = threadIdx.x;
    const int CH = (NN + 255) / 256;  // 20
    int base = tid * CH;
    int s = 0;
    for (int i = 0; i < CH; i++) {
        int idx = base + i;
        if (idx < NN) s += deg[idx];
    }
    sums[tid] = s;
    __syncthreads();
    for (int off = 1; off < 256; off <<= 1) {
        int other = (tid >= off) ? sums[tid - off] : 0;
        __syncthreads();
        sums[tid] += other;
        __syncthreads();
    }
    int run = sums[tid] - s;
    for (int i = 0; i < CH; i++) {
        int idx = base + i;
        if (idx < NN) {
            rowptr[idx] = run;
            woff[idx] = run;
            run += deg[idx];
        }
    }
    if (tid == 255) rowptr[NN] = run;
}

__global__ __launch_bounds__(256) void k_scatter(
    const int* __restrict__ edges, int* __restrict__ woff, int* __restrict__ eidx)
{
    int e = blockIdx.x * 256 + threadIdx.x;
    if (e >= EE) return;
    int pos = atomicAdd(woff + edges[e], 1);
    eidx[pos] = e;
}

// ---------------------------------------------------------------- edge MLP via MFMA
// 256 threads = 4 waves; wave handles 16 rows (row = (e,t), idx = t*EE+e).
__global__ __launch_bounds__(256) void k_edge_mfma(
    const unsigned short* __restrict__ hbuf,  // bf16 [N*T][64]
    const float* __restrict__ coord,          // [N*T][4]
    const int* __restrict__ edges,
    const float* __restrict__ eattr,
    const unsigned short* __restrict__ wpack, // this layer's packed weights
    const float* __restrict__ w1tail,         // ew1 rows 128..130 : [3][64] f32
    const float* __restrict__ bias1,
    const float* __restrict__ bias2,
    const float* __restrict__ cbias1,
    const float* __restrict__ cw2v,
    unsigned short* __restrict__ mbuf,        // bf16 [E*T][64]
    float* __restrict__ trans4)               // f32 [E*T][4]
{
    __shared__ unsigned short w_lds[WPACK_PER_LAYER];
    __shared__ unsigned short act_a[4][16 * STR2];
    __shared__ unsigned short act_m[4][16 * STR2];
    __shared__ float cd_lds[4][16][8];   // d0,d1,d2,radial,ea0,ea1,0,0
    __shared__ float cm_lds[4][16];
    __shared__ float w1t_lds[192];

    int tid = threadIdx.x;
    // ---- stage packed weights (35840 B) ----
    {
        const uint4* src = (const uint4*)wpack;
        uint4* dst = (uint4*)w_lds;
        #pragma unroll
        for (int i = 0; i < 9; i++) {
            int p = i * 256 + tid;
            if (p < WPACK_PER_LAYER / 8) dst[p] = src[p];
        }
        if (tid < 192) w1t_lds[tid] = w1tail[tid];
    }

    int wave = tid >> 6, lane = tid & 63;
    int rowbase = blockIdx.x * 64 + wave * 16;
    int g = lane >> 4, c = lane & 15;

    // ---- per-row meta (coord diff, radial, edge attr): lanes 0..15 ----
    if (lane < 16) {
        int idx = rowbase + lane;
        int e = idx % EE, t = idx / EE;
        int rr = edges[e], cc = edges[EE + e];
        float4 cr = *(const float4*)(coord + (size_t)(rr * TT + t) * 4);
        float4 cl = *(const float4*)(coord + (size_t)(cc * TT + t) * 4);
        float d0 = cr.x - cl.x, d1 = cr.y - cl.y, d2 = cr.z - cl.z;
        float rad = d0 * d0 + d1 * d1 + d2 * d2;
        float4 v0; v0.x = d0; v0.y = d1; v0.z = d2; v0.w = rad;
        float4 v1; v1.x = eattr[e * 2]; v1.y = eattr[e * 2 + 1]; v1.z = 0.f; v1.w = 0.f;
        *(float4*)&cd_lds[wave][lane][0] = v0;
        *(float4*)&cd_lds[wave][lane][4] = v1;
    }
    __syncthreads();

    // A-side global pointers: this lane serves A-row (rowbase + c)
    int aidx = rowbase + c;
    int ae = aidx % EE, at = aidx / EE;
    const unsigned short* hr = hbuf + (size_t)(edges[ae] * TT + at) * 64;
    const unsigned short* hc = hbuf + (size_t)(edges[EE + ae] * TT + at) * 64;

    // ---- layer 1: [h_row | h_col] @ W1(k<128) + tail(radial,ea) + b1 ----
    f32x4 acc[4];
    {
        float rad_r[4], e0_r[4], e1_r[4];
        #pragma unroll
        for (int r = 0; r < 4; r++) {
            rad_r[r] = cd_lds[wave][4 * g + r][3];
            e0_r[r]  = cd_lds[wave][4 * g + r][4];
            e1_r[r]  = cd_lds[wave][4 * g + r][5];
        }
        #pragma unroll
        for (int nt = 0; nt < 4; nt++) {
            int col = nt * 16 + c;
            float bb = bias1[col];
            float w0 = w1t_lds[col], wa = w1t_lds[64 + col], wb = w1t_lds[128 + col];
            #pragma unroll
            for (int r = 0; r < 4; r++)
                acc[nt][r] = bb + rad_r[r] * w0 + e0_r[r] * wa + e1_r[r] * wb;
        }
    }
    #pragma unroll
    for (int ks = 0; ks < 4; ks++) {
        const unsigned short* ap = (ks < 2 ? hr : hc) + (ks & 1) * 32 + g * 8;
        short8 af = *(const short8*)ap;
        #pragma unroll
        for (int nt = 0; nt < 4; nt++) {
            short8 bf = *(const short8*)&w_lds[WT1_OFF + (nt * 16 + c) * STR1 + ks * 32 + g * 8];
            acc[nt] = __builtin_amdgcn_mfma_f32_16x16x32_bf16(af, bf, acc[nt], 0, 0, 0);
        }
    }
    #pragma unroll
    for (int nt = 0; nt < 4; nt++)
        #pragma unroll
        for (int r = 0; r < 4; r++)
            act_a[wave][(4 * g + r) * STR2 + nt * 16 + c] = f2bf(silu_f(acc[nt][r]));

    // ---- layer 2: m = silu(a1 @ W2 + b2) ----
    f32x4 acc2[4];
    #pragma unroll
    for (int nt = 0; nt < 4; nt++) {
        float bb = bias2[nt * 16 + c];
        #pragma unroll
        for (int r = 0; r < 4; r++) acc2[nt][r] = bb;
    }
    #pragma unroll
    for (int ks = 0; ks < 2; ks++) {
        short8 af = *(const short8*)&act_a[wave][c * STR2 + ks * 32 + g * 8];
        #pragma unroll
        for (int nt = 0; nt < 4; nt++) {
            short8 bf = *(const short8*)&w_lds[WT2_OFF + (nt * 16 + c) * STR2 + ks * 32 + g * 8];
            acc2[nt] = __builtin_amdgcn_mfma_f32_16x16x32_bf16(af, bf, acc2[nt], 0, 0, 0);
        }
    }
    #pragma unroll
    for (int nt = 0; nt < 4; nt++)
        #pragma unroll
        for (int r = 0; r < 4; r++)
            act_m[wave][(4 * g + r) * STR2 + nt * 16 + c] = f2bf(silu_f(acc2[nt][r]));

    // ---- coord MLP: c1 = silu(m @ CW1 + cb1); cm = c1 . cw2 ----
    f32x4 acc3[4];
    #pragma unroll
    for (int nt = 0; nt < 4; nt++) {
        float bb = cbias1[nt * 16 + c];
        #pragma unroll
        for (int r = 0; r < 4; r++) acc3[nt][r] = bb;
    }
    #pragma unroll
    for (int ks = 0; ks < 2; ks++) {
        short8 af = *(const short8*)&act_m[wave][c * STR2 + ks * 32 + g * 8];
        #pragma unroll
        for (int nt = 0; nt < 4; nt++) {
            short8 bf = *(const short8*)&w_lds[CT1_OFF + (nt * 16 + c) * STR2 + ks * 32 + g * 8];
            acc3[nt] = __builtin_amdgcn_mfma_f32_16x16x32_bf16(af, bf, acc3[nt], 0, 0, 0);
        }
    }
    float pr[4] = {0.f, 0.f, 0.f, 0.f};
    #pragma unroll
    for (int nt = 0; nt < 4; nt++) {
        float wv = cw2v[nt * 16 + c];
        #pragma unroll
        for (int r = 0; r < 4; r++) pr[r] += silu_f(acc3[nt][r]) * wv;
    }
    #pragma unroll
    for (int off = 1; off < 16; off <<= 1) {
        #pragma unroll
        for (int r = 0; r < 4; r++) pr[r] += __shfl_xor(pr[r], off);
    }
    if (c == 0) {
        #pragma unroll
        for (int r = 0; r < 4; r++) cm_lds[wave][4 * g + r] = pr[r];
    }

    // ---- epilogue: trans4 + mbuf ----
    if (lane < 16) {
        int idx = rowbase + lane;
        int e = idx % EE, t = idx / EE;
        float cmv = cm_lds[wave][lane];
        float4 o;
        o.x = cd_lds[wave][lane][0] * cmv;
        o.y = cd_lds[wave][lane][1] * cmv;
        o.z = cd_lds[wave][lane][2] * cmv;
        o.w = 0.0f;
        *(float4*)(trans4 + (size_t)(e * TT + t) * 4) = o;
    }
    {
        int rm = lane >> 2, ch = lane & 3;
        int idx = rowbase + rm;
        int e = idx % EE, t = idx / EE;
        unsigned short* dst = mbuf + (size_t)(e * TT + t) * 64 + ch * 16;
        short8 v0 = *(const short8*)&act_m[wave][rm * STR2 + ch * 16];
        short8 v1 = *(const short8*)&act_m[wave][rm * STR2 + ch * 16 + 8];
        *(short8*)dst = v0;
        *(short8*)(dst + 8) = v1;
    }
}

// ---------------------------------------------------------------- gather: magg + coord update
__global__ __launch_bounds__(64) void k_gather(
    const unsigned short* __restrict__ mbuf, const float* __restrict__ trans4,
    const int* __restrict__ rowptr, const int* __restrict__ eidx,
    float* __restrict__ magg, float* __restrict__ coord)
{
    int b = blockIdx.x;           // n*TT + t
    int n = b / TT, t = b % TT;
    int lane = threadIdx.x;
    int start = rowptr[n], end = rowptr[n + 1];

    float s = 0.0f;
    for (int i = start; i < end; i++) {
        int e = eidx[i];
        s += bf2f(mbuf[((size_t)e * TT + t) * HH + lane]);
    }
    magg[((size_t)n * TT + t) * HH + lane] = s;

    int c = lane & 3, k0 = lane >> 2;
    float p = 0.0f;
    for (int i = start + k0; i < end; i += 16) {
        int e = eidx[i];
        p += trans4[((size_t)e * TT + t) * 4 + c];
    }
    #pragma unroll
    for (int off = 4; off < 64; off <<= 1) p += __shfl_xor(p, off);
    if (lane < 3) {
        float cntf = (float)(end - start);
        coord[(size_t)b * 4 + lane] += p / fmaxf(cntf, 1.0f);
    }
}

// ---------------------------------------------------------------- node MLP (bf16 h, f32 math)
__global__ __launch_bounds__(256) void k_node(
    unsigned short* __restrict__ hbuf, const float* __restrict__ magg,
    const float* __restrict__ w1, const float* __restrict__ b1,
    const float* __restrict__ w2, const float* __restrict__ b2)
{
    int i = blockIdx.x * 256 + threadIdx.x;  // n*T+t
    if (i >= NN * TT) return;
    unsigned short* hp = hbuf + (size_t)i * HH;
    const float* mp = magg + (size_t)i * HH;

    float a[HH];
    #pragma unroll
    for (int j = 0; j < HH; j++) a[j] = b1[j];

    for (int k0 = 0; k0 < HH; k0 += 8) {
        short8 hv = *(const short8*)(hp + k0);
        #pragma unroll
        for (int kk = 0; kk < 8; kk++) {
            float s = bf2f((unsigned short)hv[kk]);
            const float* w = w1 + (size_t)(k0 + kk) * HH;
            #pragma unroll
            for (int j = 0; j < HH; j++) a[j] += s * w[j];
        }
    }
    for (int k0 = 0; k0 < HH; k0 += 4) {
        float4 v = *(const float4*)(mp + k0);
        float s4[4] = {v.x, v.y, v.z, v.w};
        #pragma unroll
        for (int kk = 0; kk < 4; kk++) {
            const float* w = w1 + (size_t)(HH + k0 + kk) * HH;
            #pragma unroll
            for (int j = 0; j < HH; j++) a[j] += s4[kk] * w[j];
        }
    }
    #pragma unroll
    for (int j = 0; j < HH; j++) a[j] = silu_f(a[j]);

    float o[HH];
    #pragma unroll
    for (int j = 0; j < HH; j++) o[j] = b2[j];
    #pragma unroll
    for (int k = 0; k < HH; k++) {
        const float* w = w2 + (size_t)k * HH;
        float s = a[k];
        #pragma unroll
        for (int j = 0; j < HH; j++) o[j] += s * w[j];
    }
    for (int j0 = 0; j0 < HH; j0 += 8) {
        short8 hv = *(const short8*)(hp + j0);
        short8 outv;
        #pragma unroll
        for (int jj = 0; jj < 8; jj++)
            outv[jj] = (short)f2bf(bf2f((unsigned short)hv[jj]) + o[j0 + jj]);
        *(short8*)(hp + j0) = outv;
    }
}

// ---------------------------------------------------------------- readout
__global__ __launch_bounds__(256) void k_final(
    const float* __restrict__ coord, const float* __restrict__ theta,
    float* __restrict__ out)
{
    int i = blockIdx.x * 256 + threadIdx.x;  // f*N + n
    if (i >= FOUT * NN) return;
    int f = i / NN, n = i % NN;

    float w[TT];
    float mx = -1e30f;
    #pragma unroll
    for (int t = 0; t < TT; t++) { w[t] = theta[f * TT + t]; mx = fmaxf(mx, w[t]); }
    float s = 0.0f;
    #pragma unroll
    for (int t = 0; t < TT; t++) { w[t] = __expf(w[t] - mx); s += w[t]; }
    float inv = 1.0f / s;
    float o0 = 0.f, o1 = 0.f, o2 = 0.f;
    #pragma unroll
    for (int t = 0; t < TT; t++) {
        float4 cv = *(const float4*)(coord + (size_t)(n * TT + t) * 4);
        float ww = w[t] * inv;
        o0 += ww * cv.x; o1 += ww * cv.y; o2 += ww * cv.z;
    }
    float* op = out + (size_t)(f * NN + n) * 3;
    op[0] = o0; op[1] = o1; op[2] = o2;
}

extern "C" void kernel_launch(void* const* d_in, const int* in_sizes, int n_in,
                              void* d_out, int out_size, void* d_ws, size_t ws_size,
                              hipStream_t stream)
{
    const float* h_in     = (const float*)d_in[0];
    const float* x        = (const float*)d_in[1];
    const int*   edges    = (const int*)d_in[2];
    const float* eattr    = (const float*)d_in[3];
    const float* emb_w    = (const float*)d_in[4];
    const float* emb_b    = (const float*)d_in[5];
    const float* time_emb = (const float*)d_in[6];
    const float* theta    = (const float*)d_in[7];
    const float* ew1 = (const float*)d_in[8];
    const float* eb1 = (const float*)d_in[9];
    const float* ew2 = (const float*)d_in[10];
    const float* eb2 = (const float*)d_in[11];
    const float* nw1 = (const float*)d_in[12];
    const float* nb1 = (const float*)d_in[13];
    const float* nw2 = (const float*)d_in[14];
    const float* nb2 = (const float*)d_in[15];
    const float* cw1 = (const float*)d_in[16];
    const float* cb1 = (const float*)d_in[17];
    const float* cw2 = (const float*)d_in[18];
    float* out = (float*)d_out;

    // ---- workspace carve (16B-aligned chunks) ----
    char* wsb = (char*)d_ws;
    unsigned short* hbuf = (unsigned short*)wsb;            wsb += (size_t)NN * TT * HH * 2;   // 6.4 MB
    float* coord = (float*)wsb;                             wsb += (size_t)NN * TT * 4 * 4;    // 0.8 MB
    float* magg  = (float*)wsb;                             wsb += (size_t)NN * TT * HH * 4;   // 12.8 MB
    unsigned short* mbuf = (unsigned short*)wsb;            wsb += (size_t)EE * TT * HH * 2;   // 102.4 MB
    float* trans4 = (float*)wsb;                            wsb += (size_t)EE * TT * 4 * 4;    // 12.8 MB
    unsigned short* wpack = (unsigned short*)wsb;           wsb += (size_t)LL * WPACK_PER_LAYER * 2;
    int* deg    = (int*)wsb;                                wsb += (size_t)NN * 4;
    int* rowptr = (int*)wsb;                                wsb += (size_t)(NN + 1) * 4;
    int* woff   = (int*)wsb;                                wsb += (size_t)NN * 4 + 4;
    int* eidx   = (int*)wsb;                                wsb += (size_t)EE * 4;

    // ---- init + prep + CSR ----
    hipLaunchKernelGGL(k_init_h, dim3((NN * TT * HH + 255) / 256), dim3(256), 0, stream,
                       h_in, emb_w, emb_b, time_emb, hbuf);
    hipLaunchKernelGGL(k_init_coord, dim3((NN * TT + 255) / 256), dim3(256), 0, stream,
                       x, coord);
    hipLaunchKernelGGL(k_prep, dim3((LL * WPACK_PER_LAYER + 255) / 256), dim3(256), 0, stream,
                       ew1, ew2, cw1, wpack);
    hipMemsetAsync(deg, 0, (size_t)NN * sizeof(int), stream);
    hipLaunchKernelGGL(k_deg, dim3((EE + 255) / 256), dim3(256), 0, stream, edges, deg);
    hipLaunchKernelGGL(k_scan, dim3(1), dim3(256), 0, stream, deg, rowptr, woff);
    hipLaunchKernelGGL(k_scatter, dim3((EE + 255) / 256), dim3(256), 0, stream,
                       edges, woff, eidx);

    for (int l = 0; l < LL; l++) {
        hipLaunchKernelGGL(k_edge_mfma, dim3(EE * TT / 64), dim3(256), 0, stream,
            hbuf, coord, edges, eattr,
            wpack + (size_t)l * WPACK_PER_LAYER,
            ew1 + (size_t)l * 131 * 64 + 128 * 64,
            eb1 + (size_t)l * 64, eb2 + (size_t)l * 64,
            cb1 + (size_t)l * 64, cw2 + (size_t)l * 64,
            mbuf, trans4);
        hipLaunchKernelGGL(k_gather, dim3(NN * TT), dim3(64), 0, stream,
            mbuf, trans4, rowptr, eidx, magg, coord);
        hipLaunchKernelGGL(k_node, dim3((NN * TT + 255) / 256), dim3(256), 0, stream,
            hbuf, magg,
            nw1 + (size_t)l * 2 * HH * HH, nb1 + (size_t)l * HH,
            nw2 + (size_t)l * HH * HH, nb2 + (size_t)l * HH);
    }
    hipLaunchKernelGGL(k_final, dim3((FOUT * NN + 255) / 256), dim3(256), 0, stream,
        coord, theta, out);
}

// Round 4
// 735.561 us; speedup vs baseline: 18.4414x; 1.6500x over previous
//
#include <hip/hip_runtime.h>
#include <hip/hip_bf16.h>

#define NN 5000
#define TT 10
#define FOUT 8
#define HH 64
#define EE 80000
#define LL 4

#define STR1 136            // K=128 weight pack k-stride (u16)
#define STR2 72             // K=64 weight pack k-stride (u16)

// edge wpack section offsets (u16, per layer)
#define EWT1 0              // 64*136 = 8704   : edge_w1 rows 0..127, transposed [col][k]
#define EWT2 8704           // 64*72  = 4608   : edge_w2 [col][k]
#define ECT1 13312          // 64*72  = 4608   : coord_w1 [col][k]
#define ETL1 17920          // 64*8   = 512    : [col][8] = {w_rad, w_ea0, w_ea1, b1, 0,0,0,0}
#define ETB2 18432          // 64*8   = 512    : [col][8] = {b2, 0...}
#define ETC1 18944          // 64*8   = 512    : [col][8] = {cb1, 0...}
#define EDGE_WPACK 19456    // u16 per layer (38912 B)

// node wpack sections
#define NWT1 0              // 8704 : node_w1 [col][k] k<128
#define NWT2 8704           // 4608 : node_w2 [col][k]
#define NTL1 13312          // 512  : {nb1,0..}
#define NTL2 13824          // 512  : {nb2,0..}
#define NODE_WPACK 14336    // u16 per layer (28672 B)

typedef __attribute__((ext_vector_type(8))) short short8;
typedef __attribute__((ext_vector_type(4))) float f32x4;

union FragU { short8 s; unsigned u[4]; unsigned short h[8]; };

__device__ __forceinline__ float silu_f(float x) {
    return x / (1.0f + __expf(-x));
}
__device__ __forceinline__ float bf2f(unsigned short u) {
    return __uint_as_float(((unsigned int)u) << 16);
}
__device__ __forceinline__ unsigned short f2bf(float x) {   // RNE
    unsigned int u = __float_as_uint(x);
    u += 0x7fffu + ((u >> 16) & 1u);
    return (unsigned short)(u >> 16);
}
__device__ __forceinline__ unsigned pkbf(float lo, float hi) {
    unsigned r;
    asm("v_cvt_pk_bf16_f32 %0, %1, %2" : "=v"(r) : "v"(lo), "v"(hi));
    return r;
}

// ---------------------------------------------------------------- init
__global__ __launch_bounds__(256) void k_init_h(
    const float* __restrict__ h_in, const float* __restrict__ emb_w,
    const float* __restrict__ emb_b, const float* __restrict__ time_emb,
    unsigned short* __restrict__ hbuf)
{
    int idx = blockIdx.x * 256 + threadIdx.x;   // over N*T*HH
    if (idx >= NN * TT * HH) return;
    int j  = idx & (HH - 1);
    int nt = idx / HH;
    int t  = nt % TT;
    int n  = nt / TT;
    hbuf[idx] = f2bf(h_in[n] * emb_w[j] + emb_b[j] + time_emb[t * HH + j]);
}

__global__ __launch_bounds__(256) void k_init_coord(
    const float* __restrict__ x, float* __restrict__ coord)
{
    int i = blockIdx.x * 256 + threadIdx.x;  // over N*T
    if (i >= NN * TT) return;
    int t = i % TT, n = i / TT;
    const float* src = x + (size_t)(t * NN + n) * 3;
    float4 v;
    v.x = src[0]; v.y = src[1]; v.z = src[2]; v.w = 0.0f;
    *(float4*)(coord + (size_t)i * 4) = v;
}

// ---------------------------------------------------------------- weight prep
__global__ __launch_bounds__(256) void k_prep(
    const float* __restrict__ ew1, const float* __restrict__ eb1,
    const float* __restrict__ ew2, const float* __restrict__ eb2,
    const float* __restrict__ cw1, const float* __restrict__ cb1,
    const float* __restrict__ nw1, const float* __restrict__ nb1,
    const float* __restrict__ nw2, const float* __restrict__ nb2,
    unsigned short* __restrict__ wpack)
{
    const int ETOT = LL * EDGE_WPACK;
    const int TOT  = ETOT + LL * NODE_WPACK;
    int idx = blockIdx.x * 256 + threadIdx.x;
    if (idx >= TOT) return;
    float v = 0.0f;
    if (idx < ETOT) {
        int l = idx / EDGE_WPACK, o = idx % EDGE_WPACK;
        if (o < EWT2) {
            int cc = o / STR1, k = o % STR1;
            if (k < 128) v = ew1[(size_t)l * 131 * 64 + (size_t)k * 64 + cc];
        } else if (o < ECT1) {
            int o2 = o - EWT2; int cc = o2 / STR2, k = o2 % STR2;
            if (k < 64) v = ew2[(size_t)l * 4096 + (size_t)k * 64 + cc];
        } else if (o < ETL1) {
            int o2 = o - ECT1; int cc = o2 / STR2, k = o2 % STR2;
            if (k < 64) v = cw1[(size_t)l * 4096 + (size_t)k * 64 + cc];
        } else if (o < ETB2) {
            int o2 = o - ETL1; int cc = o2 >> 3, j = o2 & 7;
            if (j == 0) v = ew1[(size_t)l * 131 * 64 + 128 * 64 + cc];
            else if (j == 1) v = ew1[(size_t)l * 131 * 64 + 129 * 64 + cc];
            else if (j == 2) v = ew1[(size_t)l * 131 * 64 + 130 * 64 + cc];
            else if (j == 3) v = eb1[l * 64 + cc];
        } else if (o < ETC1) {
            int o2 = o - ETB2; int cc = o2 >> 3, j = o2 & 7;
            if (j == 0) v = eb2[l * 64 + cc];
        } else {
            int o2 = o - ETC1; int cc = o2 >> 3, j = o2 & 7;
            if (j == 0) v = cb1[l * 64 + cc];
        }
    } else {
        int q = idx - ETOT;
        int l = q / NODE_WPACK, o = q % NODE_WPACK;
        if (o < NWT2) {
            int cc = o / STR1, k = o % STR1;
            if (k < 128) v = nw1[(size_t)l * 128 * 64 + (size_t)k * 64 + cc];
        } else if (o < NTL1) {
            int o2 = o - NWT2; int cc = o2 / STR2, k = o2 % STR2;
            if (k < 64) v = nw2[(size_t)l * 4096 + (size_t)k * 64 + cc];
        } else if (o < NTL2) {
            int o2 = o - NTL1; int cc = o2 >> 3, j = o2 & 7;
            if (j == 0) v = nb1[l * 64 + cc];
        } else {
            int o2 = o - NTL2; int cc = o2 >> 3, j = o2 & 7;
            if (j == 0) v = nb2[l * 64 + cc];
        }
    }
    wpack[idx] = f2bf(v);
}

// ---------------------------------------------------------------- CSR build
__global__ __launch_bounds__(256) void k_deg(
    const int* __restrict__ edges, int* __restrict__ deg)
{
    int e = blockIdx.x * 256 + threadIdx.x;
    if (e >= EE) return;
    atomicAdd(deg + edges[e], 1);
}

__global__ __launch_bounds__(256) void k_scan(
    const int* __restrict__ deg, int* __restrict__ rowptr, int* __restrict__ woff)
{
    __shared__ int sums[256];
    int tid = threadIdx.x;
    const int CH = (NN + 255) / 256;  // 20
    int base = tid * CH;
    int s = 0;
    for (int i = 0; i < CH; i++) {
        int idx = base + i;
        if (idx < NN) s += deg[idx];
    }
    sums[tid] = s;
    __syncthreads();
    for (int off = 1; off < 256; off <<= 1) {
        int other = (tid >= off) ? sums[tid - off] : 0;
        __syncthreads();
        sums[tid] += other;
        __syncthreads();
    }
    int run = sums[tid] - s;
    for (int i = 0; i < CH; i++) {
        int idx = base + i;
        if (idx < NN) {
            rowptr[idx] = run;
            woff[idx] = run;
            run += deg[idx];
        }
    }
    if (tid == 255) rowptr[NN] = run;
}

__global__ __launch_bounds__(256) void k_scatter(
    const int* __restrict__ edges, int* __restrict__ woff, int* __restrict__ eidx)
{
    int e = blockIdx.x * 256 + threadIdx.x;
    if (e >= EE) return;
    int pos = atomicAdd(woff + edges[e], 1);
    eidx[pos] = e;
}

// ---------------------------------------------------------------- edge MLP, transposed MFMA
// D = W^T(A) * X^T(B). Lane (g,c): A-row = out-col (nt*16+c), k = 8g..8g+7.
// B-col = edge-row c, k = 8g..8g+7. C: lane holds D[out-col 16nt+4g+r][edge-row c].
__global__ __launch_bounds__(256) void k_edge_mfma(
    const unsigned short* __restrict__ hbuf,  // bf16 [N*T][64]
    const float* __restrict__ coord,          // [N*T][4]
    const int* __restrict__ edges,
    const float* __restrict__ eattr,
    const unsigned short* __restrict__ wpack, // this layer's packed weights
    const float* __restrict__ cw2v,           // [64] f32
    unsigned short* __restrict__ mbuf,        // bf16 [E*T][64]
    float* __restrict__ trans4)               // f32 [E*T][4]
{
    __shared__ __align__(16) unsigned short w_lds[EDGE_WPACK];
    int tid = threadIdx.x;
    {
        const uint4* src = (const uint4*)wpack;
        uint4* dst = (uint4*)w_lds;
        #pragma unroll
        for (int i = 0; i < 10; i++) {
            int p = i * 256 + tid;
            if (p < EDGE_WPACK / 8) dst[p] = src[p];
        }
    }
    __syncthreads();

    int wave = tid >> 6, lane = tid & 63;
    int g = lane >> 4, c = lane & 15;
    bool g0 = (g == 0);
    bool selhi = (g >= 2);
    int L0 = ((g & 1) << 5) + c, L1 = L0 + 16;

    int idx = blockIdx.x * 64 + wave * 16 + c;       // row = (e,t), all g dup row c
    int e = idx % EE, t = idx / EE;
    int rn = edges[e], cn = edges[EE + e];
    int rt = rn * TT + t, ct = cn * TT + t;
    float4 cr = *(const float4*)(coord + (size_t)rt * 4);
    float4 cl = *(const float4*)(coord + (size_t)ct * 4);
    float d0 = cr.x - cl.x, d1 = cr.y - cl.y, d2 = cr.z - cl.z;
    float rad = d0 * d0 + d1 * d1 + d2 * d2;
    float2 ea = *(const float2*)(eattr + 2 * e);

    // B-frags layer1 (global, k = [h_row | h_col])
    const unsigned short* hr = hbuf + (size_t)rt * 64;
    const unsigned short* hc = hbuf + (size_t)ct * 64;
    FragU bh[4];
    bh[0].s = *(const short8*)(hr + g * 8);
    bh[1].s = *(const short8*)(hr + 32 + g * 8);
    bh[2].s = *(const short8*)(hc + g * 8);
    bh[3].s = *(const short8*)(hc + 32 + g * 8);

    FragU btail; btail.u[0] = btail.u[1] = btail.u[2] = btail.u[3] = 0;
    if (g0) { btail.u[0] = pkbf(rad, ea.x); btail.u[1] = pkbf(ea.y, 1.0f); }
    FragU bone; bone.u[0] = bone.u[1] = bone.u[2] = bone.u[3] = 0;
    if (g0) bone.u[0] = 0x3F80u;     // bf16(1.0) in k=0 slot

    // ---- layer 1: K=128 + tail tile (rad, ea0, ea1, bias) ----
    f32x4 acc[4];
    #pragma unroll
    for (int nt = 0; nt < 4; nt++) acc[nt] = (f32x4){0.f, 0.f, 0.f, 0.f};
    #pragma unroll
    for (int ks = 0; ks < 4; ks++) {
        #pragma unroll
        for (int nt = 0; nt < 4; nt++) {
            short8 af = *(const short8*)&w_lds[EWT1 + (nt * 16 + c) * STR1 + ks * 32 + g * 8];
            acc[nt] = __builtin_amdgcn_mfma_f32_16x16x32_bf16(af, bh[ks].s, acc[nt], 0, 0, 0);
        }
    }
    #pragma unroll
    for (int nt = 0; nt < 4; nt++) {
        FragU af; af.u[0] = af.u[1] = af.u[2] = af.u[3] = 0;
        if (g0) af.s = *(const short8*)&w_lds[ETL1 + (nt * 16 + c) * 8];
        acc[nt] = __builtin_amdgcn_mfma_f32_16x16x32_bf16(af.s, btail.s, acc[nt], 0, 0, 0);
    }

    // ---- silu + in-register transpose to next-layer B-frags ----
    unsigned uLo[4], uHi[4];
    #pragma unroll
    for (int nt = 0; nt < 4; nt++) {
        uLo[nt] = pkbf(silu_f(acc[nt][0]), silu_f(acc[nt][1]));
        uHi[nt] = pkbf(silu_f(acc[nt][2]), silu_f(acc[nt][3]));
    }
    FragU b2[2];
    #pragma unroll
    for (int ks = 0; ks < 2; ks++) {
        int a0 = __shfl((int)uLo[2 * ks], L0), a1 = __shfl((int)uLo[2 * ks + 1], L0);
        int b0 = __shfl((int)uHi[2 * ks], L0), b1 = __shfl((int)uHi[2 * ks + 1], L0);
        b2[ks].u[0] = selhi ? a1 : a0;
        b2[ks].u[1] = selhi ? b1 : b0;
        a0 = __shfl((int)uLo[2 * ks], L1); a1 = __shfl((int)uLo[2 * ks + 1], L1);
        b0 = __shfl((int)uHi[2 * ks], L1); b1 = __shfl((int)uHi[2 * ks + 1], L1);
        b2[ks].u[2] = selhi ? a1 : a0;
        b2[ks].u[3] = selhi ? b1 : b0;
    }

    // ---- layer 2: K=64 + bias tile ----
    f32x4 acc2[4];
    #pragma unroll
    for (int nt = 0; nt < 4; nt++) acc2[nt] = (f32x4){0.f, 0.f, 0.f, 0.f};
    #pragma unroll
    for (int ks = 0; ks < 2; ks++) {
        #pragma unroll
        for (int nt = 0; nt < 4; nt++) {
            short8 af = *(const short8*)&w_lds[EWT2 + (nt * 16 + c) * STR2 + ks * 32 + g * 8];
            acc2[nt] = __builtin_amdgcn_mfma_f32_16x16x32_bf16(af, b2[ks].s, acc2[nt], 0, 0, 0);
        }
    }
    #pragma unroll
    for (int nt = 0; nt < 4; nt++) {
        FragU af; af.u[0] = af.u[1] = af.u[2] = af.u[3] = 0;
        if (g0) af.s = *(const short8*)&w_lds[ETB2 + (nt * 16 + c) * 8];
        acc2[nt] = __builtin_amdgcn_mfma_f32_16x16x32_bf16(af.s, bone.s, acc2[nt], 0, 0, 0);
    }

    // ---- silu -> m; exchange to B-frags (= m bf16, store to mbuf) ----
    #pragma unroll
    for (int nt = 0; nt < 4; nt++) {
        uLo[nt] = pkbf(silu_f(acc2[nt][0]), silu_f(acc2[nt][1]));
        uHi[nt] = pkbf(silu_f(acc2[nt][2]), silu_f(acc2[nt][3]));
    }
    FragU b3[2];
    #pragma unroll
    for (int ks = 0; ks < 2; ks++) {
        int a0 = __shfl((int)uLo[2 * ks], L0), a1 = __shfl((int)uLo[2 * ks + 1], L0);
        int b0 = __shfl((int)uHi[2 * ks], L0), b1 = __shfl((int)uHi[2 * ks + 1], L0);
        b3[ks].u[0] = selhi ? a1 : a0;
        b3[ks].u[1] = selhi ? b1 : b0;
        a0 = __shfl((int)uLo[2 * ks], L1); a1 = __shfl((int)uLo[2 * ks + 1], L1);
        b0 = __shfl((int)uHi[2 * ks], L1); b1 = __shfl((int)uHi[2 * ks + 1], L1);
        b3[ks].u[2] = selhi ? a1 : a0;
        b3[ks].u[3] = selhi ? b1 : b0;
    }
    unsigned short* mp = mbuf + ((size_t)e * TT + t) * 64;
    *(uint4*)(mp + 8 * g)      = *(uint4*)b3[0].u;
    *(uint4*)(mp + 32 + 8 * g) = *(uint4*)b3[1].u;

    // ---- coord MLP: c1 = silu(m @ CW1 + cb1); cm = c1 . cw2 ----
    f32x4 acc3[4];
    #pragma unroll
    for (int nt = 0; nt < 4; nt++) acc3[nt] = (f32x4){0.f, 0.f, 0.f, 0.f};
    #pragma unroll
    for (int ks = 0; ks < 2; ks++) {
        #pragma unroll
        for (int nt = 0; nt < 4; nt++) {
            short8 af = *(const short8*)&w_lds[ECT1 + (nt * 16 + c) * STR2 + ks * 32 + g * 8];
            acc3[nt] = __builtin_amdgcn_mfma_f32_16x16x32_bf16(af, b3[ks].s, acc3[nt], 0, 0, 0);
        }
    }
    #pragma unroll
    for (int nt = 0; nt < 4; nt++) {
        FragU af; af.u[0] = af.u[1] = af.u[2] = af.u[3] = 0;
        if (g0) af.s = *(const short8*)&w_lds[ETC1 + (nt * 16 + c) * 8];
        acc3[nt] = __builtin_amdgcn_mfma_f32_16x16x32_bf16(af.s, bone.s, acc3[nt], 0, 0, 0);
    }
    float p = 0.0f;
    #pragma unroll
    for (int nt = 0; nt < 4; nt++) {
        #pragma unroll
        for (int r = 0; r < 4; r++)
            p += silu_f(acc3[nt][r]) * cw2v[nt * 16 + 4 * g + r];
    }
    p += __shfl_xor(p, 16);
    p += __shfl_xor(p, 32);
    if (g0) {
        float4 o; o.x = d0 * p; o.y = d1 * p; o.z = d2 * p; o.w = 0.0f;
        *(float4*)(trans4 + ((size_t)e * TT + t) * 4) = o;
    }
}

// ---------------------------------------------------------------- gather: magg(bf16) + coord update
__global__ __launch_bounds__(64) void k_gather(
    const unsigned short* __restrict__ mbuf, const float* __restrict__ trans4,
    const int* __restrict__ rowptr, const int* __restrict__ eidx,
    unsigned short* __restrict__ maggb, float* __restrict__ coord)
{
    int b = blockIdx.x;           // n*TT + t
    int n = b / TT, t = b % TT;
    int lane = threadIdx.x;
    int start = rowptr[n], end = rowptr[n + 1];

    float s = 0.0f;
    for (int i = start; i < end; i++) {
        int e = eidx[i];
        s += bf2f(mbuf[((size_t)e * TT + t) * HH + lane]);
    }
    maggb[((size_t)n * TT + t) * HH + lane] = f2bf(s);

    int c = lane & 3, k0 = lane >> 2;
    float p = 0.0f;
    for (int i = start + k0; i < end; i += 16) {
        int e = eidx[i];
        p += trans4[((size_t)e * TT + t) * 4 + c];
    }
    #pragma unroll
    for (int off = 4; off < 64; off <<= 1) p += __shfl_xor(p, off);
    if (lane < 3) {
        float cntf = (float)(end - start);
        coord[(size_t)b * 4 + lane] += p / fmaxf(cntf, 1.0f);
    }
}

// ---------------------------------------------------------------- node MLP via MFMA (residual)
__global__ __launch_bounds__(256) void k_node_mfma(
    unsigned short* __restrict__ hbuf,
    const unsigned short* __restrict__ maggb,
    const unsigned short* __restrict__ wpack)
{
    __shared__ __align__(16) unsigned short w_lds[NODE_WPACK];
    int tid = threadIdx.x;
    {
        const uint4* src = (const uint4*)wpack;
        uint4* dst = (uint4*)w_lds;
        #pragma unroll
        for (int i = 0; i < 7; i++) dst[i * 256 + tid] = src[i * 256 + tid];  // 1792 exact
    }
    __syncthreads();

    int wave = tid >> 6, lane = tid & 63;
    int g = lane >> 4, c = lane & 15;
    bool g0 = (g == 0);
    bool selhi = (g >= 2);
    int L0 = ((g & 1) << 5) + c, L1 = L0 + 16;

    int idx = blockIdx.x * 64 + wave * 16 + c;
    bool valid = idx < NN * TT;
    int row = valid ? idx : 0;
    const unsigned short* hp = hbuf + (size_t)row * 64;
    const unsigned short* mp = maggb + (size_t)row * 64;
    FragU bh[4];
    bh[0].s = *(const short8*)(hp + g * 8);
    bh[1].s = *(const short8*)(hp + 32 + g * 8);
    bh[2].s = *(const short8*)(mp + g * 8);
    bh[3].s = *(const short8*)(mp + 32 + g * 8);
    FragU bone; bone.u[0] = bone.u[1] = bone.u[2] = bone.u[3] = 0;
    if (g0) bone.u[0] = 0x3F80u;

    // layer 1 + bias tile
    f32x4 acc[4];
    #pragma unroll
    for (int nt = 0; nt < 4; nt++) acc[nt] = (f32x4){0.f, 0.f, 0.f, 0.f};
    #pragma unroll
    for (int ks = 0; ks < 4; ks++) {
        #pragma unroll
        for (int nt = 0; nt < 4; nt++) {
            short8 af = *(const short8*)&w_lds[NWT1 + (nt * 16 + c) * STR1 + ks * 32 + g * 8];
            acc[nt] = __builtin_amdgcn_mfma_f32_16x16x32_bf16(af, bh[ks].s, acc[nt], 0, 0, 0);
        }
    }
    #pragma unroll
    for (int nt = 0; nt < 4; nt++) {
        FragU af; af.u[0] = af.u[1] = af.u[2] = af.u[3] = 0;
        if (g0) af.s = *(const short8*)&w_lds[NTL1 + (nt * 16 + c) * 8];
        acc[nt] = __builtin_amdgcn_mfma_f32_16x16x32_bf16(af.s, bone.s, acc[nt], 0, 0, 0);
    }
    // silu + exchange
    unsigned uLo[4], uHi[4];
    #pragma unroll
    for (int nt = 0; nt < 4; nt++) {
        uLo[nt] = pkbf(silu_f(acc[nt][0]), silu_f(acc[nt][1]));
        uHi[nt] = pkbf(silu_f(acc[nt][2]), silu_f(acc[nt][3]));
    }
    FragU b2[2];
    #pragma unroll
    for (int ks = 0; ks < 2; ks++) {
        int a0 = __shfl((int)uLo[2 * ks], L0), a1 = __shfl((int)uLo[2 * ks + 1], L0);
        int b0 = __shfl((int)uHi[2 * ks], L0), b1 = __shfl((int)uHi[2 * ks + 1], L0);
        b2[ks].u[0] = selhi ? a1 : a0;
        b2[ks].u[1] = selhi ? b1 : b0;
        a0 = __shfl((int)uLo[2 * ks], L1); a1 = __shfl((int)uLo[2 * ks + 1], L1);
        b0 = __shfl((int)uHi[2 * ks], L1); b1 = __shfl((int)uHi[2 * ks + 1], L1);
        b2[ks].u[2] = selhi ? a1 : a0;
        b2[ks].u[3] = selhi ? b1 : b0;
    }
    // layer 2 + bias tile (no silu)
    f32x4 acc2[4];
    #pragma unroll
    for (int nt = 0; nt < 4; nt++) acc2[nt] = (f32x4){0.f, 0.f, 0.f, 0.f};
    #pragma unroll
    for (int ks = 0; ks < 2; ks++) {
        #pragma unroll
        for (int nt = 0; nt < 4; nt++) {
            short8 af = *(const short8*)&w_lds[NWT2 + (nt * 16 + c) * STR2 + ks * 32 + g * 8];
            acc2[nt] = __builtin_amdgcn_mfma_f32_16x16x32_bf16(af, b2[ks].s, acc2[nt], 0, 0, 0);
        }
    }
    #pragma unroll
    for (int nt = 0; nt < 4; nt++) {
        FragU af; af.u[0] = af.u[1] = af.u[2] = af.u[3] = 0;
        if (g0) af.s = *(const short8*)&w_lds[NTL2 + (nt * 16 + c) * 8];
        acc2[nt] = __builtin_amdgcn_mfma_f32_16x16x32_bf16(af.s, bone.s, acc2[nt], 0, 0, 0);
    }
    // pack out (no silu) + exchange to B-layout
    #pragma unroll
    for (int nt = 0; nt < 4; nt++) {
        uLo[nt] = pkbf(acc2[nt][0], acc2[nt][1]);
        uHi[nt] = pkbf(acc2[nt][2], acc2[nt][3]);
    }
    FragU o2[2];
    #pragma unroll
    for (int ks = 0; ks < 2; ks++) {
        int a0 = __shfl((int)uLo[2 * ks], L0), a1 = __shfl((int)uLo[2 * ks + 1], L0);
        int b0 = __shfl((int)uHi[2 * ks], L0), b1 = __shfl((int)uHi[2 * ks + 1], L0);
        o2[ks].u[0] = selhi ? a1 : a0;
        o2[ks].u[1] = selhi ? b1 : b0;
        a0 = __shfl((int)uLo[2 * ks], L1); a1 = __shfl((int)uLo[2 * ks + 1], L1);
        b0 = __shfl((int)uHi[2 * ks], L1); b1 = __shfl((int)uHi[2 * ks + 1], L1);
        o2[ks].u[2] = selhi ? a1 : a0;
        o2[ks].u[3] = selhi ? b1 : b0;
    }
    // residual (h frags bh[0], bh[1] are exactly cols 8g.. / 32+8g..) + store
    if (valid) {
        #pragma unroll
        for (int tile = 0; tile < 2; tile++) {
            FragU res;
            #pragma unroll
            for (int d = 0; d < 4; d++) {
                float a0 = bf2f(bh[tile].h[2 * d])     + bf2f((unsigned short)(o2[tile].u[d] & 0xFFFFu));
                float a1 = bf2f(bh[tile].h[2 * d + 1]) + bf2f((unsigned short)(o2[tile].u[d] >> 16));
                res.u[d] = pkbf(a0, a1);
            }
            unsigned short* dst = hbuf + (size_t)row * 64 + (tile ? 32 : 0) + 8 * g;
            *(uint4*)dst = *(uint4*)res.u;
        }
    }
}

// ---------------------------------------------------------------- readout
__global__ __launch_bounds__(256) void k_final(
    const float* __restrict__ coord, const float* __restrict__ theta,
    float* __restrict__ out)
{
    int i = blockIdx.x * 256 + threadIdx.x;  // f*N + n
    if (i >= FOUT * NN) return;
    int f = i / NN, n = i % NN;

    float w[TT];
    float mx = -1e30f;
    #pragma unroll
    for (int t = 0; t < TT; t++) { w[t] = theta[f * TT + t]; mx = fmaxf(mx, w[t]); }
    float s = 0.0f;
    #pragma unroll
    for (int t = 0; t < TT; t++) { w[t] = __expf(w[t] - mx); s += w[t]; }
    float inv = 1.0f / s;
    float o0 = 0.f, o1 = 0.f, o2 = 0.f;
    #pragma unroll
    for (int t = 0; t < TT; t++) {
        float4 cv = *(const float4*)(coord + (size_t)(n * TT + t) * 4);
        float ww = w[t] * inv;
        o0 += ww * cv.x; o1 += ww * cv.y; o2 += ww * cv.z;
    }
    float* op = out + (size_t)(f * NN + n) * 3;
    op[0] = o0; op[1] = o1; op[2] = o2;
}

extern "C" void kernel_launch(void* const* d_in, const int* in_sizes, int n_in,
                              void* d_out, int out_size, void* d_ws, size_t ws_size,
                              hipStream_t stream)
{
    const float* h_in     = (const float*)d_in[0];
    const float* x        = (const float*)d_in[1];
    const int*   edges    = (const int*)d_in[2];
    const float* eattr    = (const float*)d_in[3];
    const float* emb_w    = (const float*)d_in[4];
    const float* emb_b    = (const float*)d_in[5];
    const float* time_emb = (const float*)d_in[6];
    const float* theta    = (const float*)d_in[7];
    const float* ew1 = (const float*)d_in[8];
    const float* eb1 = (const float*)d_in[9];
    const float* ew2 = (const float*)d_in[10];
    const float* eb2 = (const float*)d_in[11];
    const float* nw1 = (const float*)d_in[12];
    const float* nb1 = (const float*)d_in[13];
    const float* nw2 = (const float*)d_in[14];
    const float* nb2 = (const float*)d_in[15];
    const float* cw1 = (const float*)d_in[16];
    const float* cb1 = (const float*)d_in[17];
    const float* cw2 = (const float*)d_in[18];
    float* out = (float*)d_out;

    // ---- workspace carve ----
    char* wsb = (char*)d_ws;
    unsigned short* hbuf  = (unsigned short*)wsb;  wsb += (size_t)NN * TT * HH * 2;
    unsigned short* maggb = (unsigned short*)wsb;  wsb += (size_t)NN * TT * HH * 2;
    float* coord = (float*)wsb;                    wsb += (size_t)NN * TT * 4 * 4;
    unsigned short* mbuf = (unsigned short*)wsb;   wsb += (size_t)EE * TT * HH * 2;
    float* trans4 = (float*)wsb;                   wsb += (size_t)EE * TT * 4 * 4;
    unsigned short* wpack = (unsigned short*)wsb;  wsb += (size_t)LL * (EDGE_WPACK + NODE_WPACK) * 2;
    int* deg    = (int*)wsb;                       wsb += (size_t)NN * 4;
    int* rowptr = (int*)wsb;                       wsb += (size_t)(NN + 1) * 4;
    int* woff   = (int*)wsb;                       wsb += (size_t)NN * 4 + 4;
    int* eidx   = (int*)wsb;                       wsb += (size_t)EE * 4;

    // ---- init + prep + CSR ----
    hipLaunchKernelGGL(k_init_h, dim3((NN * TT * HH + 255) / 256), dim3(256), 0, stream,
                       h_in, emb_w, emb_b, time_emb, hbuf);
    hipLaunchKernelGGL(k_init_coord, dim3((NN * TT + 255) / 256), dim3(256), 0, stream,
                       x, coord);
    {
        int tot = LL * (EDGE_WPACK + NODE_WPACK);
        hipLaunchKernelGGL(k_prep, dim3((tot + 255) / 256), dim3(256), 0, stream,
                           ew1, eb1, ew2, eb2, cw1, cb1, nw1, nb1, nw2, nb2, wpack);
    }
    hipMemsetAsync(deg, 0, (size_t)NN * sizeof(int), stream);
    hipLaunchKernelGGL(k_deg, dim3((EE + 255) / 256), dim3(256), 0, stream, edges, deg);
    hipLaunchKernelGGL(k_scan, dim3(1), dim3(256), 0, stream, deg, rowptr, woff);
    hipLaunchKernelGGL(k_scatter, dim3((EE + 255) / 256), dim3(256), 0, stream,
                       edges, woff, eidx);

    unsigned short* wpack_node0 = wpack + (size_t)LL * EDGE_WPACK;
    for (int l = 0; l < LL; l++) {
        hipLaunchKernelGGL(k_edge_mfma, dim3(EE * TT / 64), dim3(256), 0, stream,
            hbuf, coord, edges, eattr,
            wpack + (size_t)l * EDGE_WPACK,
            cw2 + (size_t)l * 64,
            mbuf, trans4);
        hipLaunchKernelGGL(k_gather, dim3(NN * TT), dim3(64), 0, stream,
            mbuf, trans4, rowptr, eidx, maggb, coord);
        hipLaunchKernelGGL(k_node_mfma, dim3((NN * TT + 63) / 64), dim3(256), 0, stream,
            hbuf, maggb, wpack_node0 + (size_t)l * NODE_WPACK);
    }
    hipLaunchKernelGGL(k_final, dim3((FOUT * NN + 255) / 256), dim3(256), 0, stream,
        coord, theta, out);
}